// Round 18
// baseline (656.938 us; speedup 1.0000x reference)
//
#include <hip/hip_runtime.h>
#include <hip/hip_bf16.h>
#include <math.h>

#define N_  4
#define C_  512
#define H_  64
#define W_  64
#define HW_ 4096
#define CR_ 64
#define NC_ 64
#define EPSV 1e-5f

typedef __attribute__((ext_vector_type(8))) __bf16 bf16x8;
typedef __attribute__((ext_vector_type(4))) float f32x4;
typedef __hip_bfloat16 bf16s;

__device__ __forceinline__ unsigned short bfb(float f) {
    union { bf16s h; unsigned short u; } cv;
    cv.h = __float2bfloat16(f);
    return cv.u;
}

__device__ __forceinline__ float b2f(unsigned short h) {
    union { unsigned u; float f; } c; c.u = ((unsigned)h) << 16; return c.f;
}

__device__ __forceinline__ float ex2(float x) {
    return __builtin_amdgcn_exp2f(x);        // raw v_exp_f32
}

// XOR-swizzled element offset for a [64][64] bf16 LDS tile (128 B rows,
// 8 chunks of 16 B). chunk' = chunk ^ (row&7) -> conflict-free b128 access.
__device__ __forceinline__ int swz8(int row, int ch) {
    return row * 64 + ((ch ^ (row & 7)) << 3);
}

// ---------------------------------------------------------------------------
// MERGED prologue: weight transposes + bf16 casts + s0 zero + x transpose
// in ONE launch. Blocks < 19976: flat elementwise segments. Blocks >= 19976:
// 64x64 x-transpose tiles (whole-block branch).
// ---------------------------------------------------------------------------
__global__ __launch_bounds__(256) void k_prep(
    const float* __restrict__ x,
    const float* __restrict__ Wpam, const float* __restrict__ Wcam,
    const float* __restrict__ Wq, const float* __restrict__ Wk,
    const float* __restrict__ Wv, const float* __restrict__ Wpo,
    const float* __restrict__ Wco,
    bf16s* __restrict__ xbT,
    bf16s* __restrict__ wbp, bf16s* __restrict__ wbp2,
    bf16s* __restrict__ Wqb, bf16s* __restrict__ Wkb,
    bf16s* __restrict__ Wvb, bf16s* __restrict__ Wpob,
    bf16s* __restrict__ Wcob, float* __restrict__ s0)
{
    __shared__ float xs[64][65];
    const int b = blockIdx.x;
    if (b >= 19976) {                        // x-transpose tile
        const int idx = b - 19976;           // 0..2047
        const int n   = idx >> 9;
        const int rem = idx & 511;
        const int p0  = (rem & 63) * 64;
        const int c0  = (rem >> 6) * 64;
        const int tid = threadIdx.x;
        for (int e = tid; e < 4096; e += 256) {
            int ci = e >> 6, pi = e & 63;
            xs[ci][pi] = x[((size_t)(n*C_ + c0 + ci))*HW_ + p0 + pi];
        }
        __syncthreads();
        for (int e = tid; e < 4096; e += 256) {
            int pi = e >> 6, ci = e & 63;
            xbT[((size_t)n*HW_ + p0 + pi)*C_ + c0 + ci] =
                __float2bfloat16(xs[ci][pi]);
        }
        return;
    }
    long e = (long)b * 256 + threadIdx.x;
    if (e < 2359296) {
        int c = e & 511; int r = e >> 9;
        int tap = r % 9; int o = r / 9;
        wbp[e] = __float2bfloat16(Wpam[((size_t)o*C_ + c)*9 + tap]);
        return;
    }
    e -= 2359296;
    if (e < 2359296) {
        int c = e & 511; int r = e >> 9;
        int tap = r % 9; int o = r / 9;
        wbp2[e] = __float2bfloat16(Wcam[((size_t)o*C_ + c)*9 + tap]);
        return;
    }
    e -= 2359296;
    if (e < 32768) { Wqb[e] = __float2bfloat16(Wq[e]); return; }
    e -= 32768;
    if (e < 32768) { Wkb[e] = __float2bfloat16(Wk[e]); return; }
    e -= 32768;
    if (e < 262144) { Wvb[e] = __float2bfloat16(Wv[e]); return; }
    e -= 262144;
    if (e < 32768) { Wpob[e] = __float2bfloat16(Wpo[e]); return; }
    e -= 32768;
    if (e < 32768) { Wcob[e] = __float2bfloat16(Wco[e]); return; }
    e -= 32768;
    if (e < 2048) s0[e] = 0.f;
}

// ---------------------------------------------------------------------------
// MERGED conv3x3 + BN + LReLU implicit-GEMM MFMA, PAM+CAM in one launch.
// NEW structure: A (weights) read DIRECT from global per-fragment (cb-group
// reads are contiguous 64B lines; the 24 KB panel is shared by 32 p-blocks
// per XCD -> L1/L2-served). B staged ONCE per c0 for ALL 3 dyi (4 rows x 66,
// 19 KB; removes the 2x re-stage of interior rows). Barriers: 96 -> 32.
// MFMA accumulation order (c0, dyi, dxi) identical to R17 -> bit-identical.
// ---------------------------------------------------------------------------
__global__ __launch_bounds__(256, 3) void k_conv3x3_mfma(
    const bf16s* __restrict__ xbT,
    const bf16s* __restrict__ wb,  const bf16s* __restrict__ wb2,
    const float* __restrict__ gamma,  const float* __restrict__ beta,
    const float* __restrict__ mean,   const float* __restrict__ var,
    const float* __restrict__ gamma2, const float* __restrict__ beta2,
    const float* __restrict__ mean2,  const float* __restrict__ var2,
    bf16s* __restrict__ featT, bf16s* __restrict__ featT2,
    float* __restrict__ csum)
{
    __shared__ bf16s bL[264][36];            // [ry*66+xi][ch], rows y0-1..y0+2
    const int tid = threadIdx.x;
    const int lid = blockIdx.x + (blockIdx.y << 5) + (blockIdx.z << 8);
    const int xcd = lid & 7;                 // XCD pin: (half, n) fixed per XCD
    const int half = xcd >> 2;               // 0=PAM, 1=CAM
    const int n    = xcd & 3;
    const int w8   = lid >> 3;               // 0..127
    const int o0 = (w8 >> 5) * 128;          // o-quarter: 32 consecutive blocks
    const int pt = w8 & 31;                  //   share one weight panel
    const int y0 = pt * 2;
    const bf16s* wbs = half ? wb2 : wb;
    const float* gm = half ? gamma2 : gamma;
    const float* bt = half ? beta2  : beta;
    const float* mn = half ? mean2  : mean;
    const float* vr = half ? var2   : var;
    bf16s* ft = half ? featT2 : featT;
    const int lane = tid & 63;
    const int wid  = tid >> 6;
    const int wr = wid >> 1, wc = wid & 1;
    const int lr = lane & 15, cb = lane >> 4;

    f32x4 acc[4][4];
#pragma unroll
    for (int i = 0; i < 4; ++i)
#pragma unroll
        for (int j = 0; j < 4; ++j) acc[i][j] = (f32x4){0.f,0.f,0.f,0.f};

    // B staging: 264 tokens x 4 chunks = 1056 int4; thread e handles
    // e, e+256, e+512, e+768 (always valid) and e+1024 (tid<32).
    int4 pB0, pB1, pB2, pB3, pB4;

#define CONV_BLOADK(DST, K, C0)                                               \
    {                                                                         \
        int e_ = tid + (K)*256;                                               \
        int4 v_ = {0,0,0,0};                                                  \
        if ((K) < 4 || e_ < 1056) {                                           \
            int cb2_ = e_ & 3; int t_ = e_ >> 2;                              \
            int ry_ = t_ / 66, xi_ = t_ % 66;                                 \
            int row_ = y0 - 1 + ry_;                                          \
            int xc_  = xi_ - 1;                                               \
            if (row_ >= 0 && row_ < H_ && xc_ >= 0 && xc_ < W_)               \
                v_ = *(const int4*)(xbT +                                     \
                    ((size_t)n*HW_ + row_*W_ + xc_)*C_ + (C0) + cb2_*8);      \
        }                                                                     \
        DST = v_;                                                             \
    }

#define CONV_BISSUE(C0)                                                       \
    CONV_BLOADK(pB0, 0, C0) CONV_BLOADK(pB1, 1, C0)                           \
    CONV_BLOADK(pB2, 2, C0) CONV_BLOADK(pB3, 3, C0)                           \
    CONV_BLOADK(pB4, 4, C0)

#define CONV_BCOMMITK(SRC, K)                                                 \
    {                                                                         \
        int e_ = tid + (K)*256;                                               \
        if ((K) < 4 || e_ < 1056) {                                           \
            int cb2_ = e_ & 3; int t_ = e_ >> 2;                              \
            *(int4*)&bL[t_][cb2_*8] = SRC;                                    \
        }                                                                     \
    }

    CONV_BISSUE(0)
    for (int c0 = 0; c0 < C_; c0 += 32) {
        CONV_BCOMMITK(pB0, 0) CONV_BCOMMITK(pB1, 1)
        CONV_BCOMMITK(pB2, 2) CONV_BCOMMITK(pB3, 3)
        CONV_BCOMMITK(pB4, 4)
        __syncthreads();                     // bL(c0) visible
        if (c0 + 32 < C_) CONV_BISSUE(c0 + 32)   // overlap with MFMA below
#pragma unroll
        for (int dyi = 0; dyi < 3; ++dyi) {
#pragma unroll
            for (int dxi = 0; dxi < 3; ++dxi) {
                bf16x8 af[4], bfv[4];
#pragma unroll
                for (int fm = 0; fm < 4; ++fm)
                    af[fm] = *(const bf16x8*)(wbs +
                        ((size_t)(o0 + wr*64 + fm*16 + lr)*9 + dyi*3 + dxi)*C_
                        + c0 + cb*8);
#pragma unroll
                for (int fn = 0; fn < 4; ++fn) {
                    int pg = wc*64 + fn*16 + lr;
                    int ry = pg >> 6, xc = pg & 63;
                    bfv[fn] = *(const bf16x8*)&bL[(ry + dyi)*66 + xc + dxi][cb*8];
                }
#pragma unroll
                for (int fm = 0; fm < 4; ++fm)
#pragma unroll
                    for (int fn = 0; fn < 4; ++fn)
                        acc[fm][fn] = __builtin_amdgcn_mfma_f32_16x16x32_bf16(
                            af[fm], bfv[fn], acc[fm][fn], 0, 0, 0);
            }
        }
        __syncthreads();                     // readers(c0) done
    }
#undef CONV_BISSUE
#undef CONV_BLOADK
#undef CONV_BCOMMITK
#pragma unroll
    for (int fm = 0; fm < 4; ++fm) {
        float sc[4], sh[4];
        const int obase = o0 + wr*64 + fm*16 + cb*4;
#pragma unroll
        for (int r = 0; r < 4; ++r) {
            int o = obase + r;
            sc[r] = gm[o] * rsqrtf(vr[o] + EPSV);
            sh[r] = bt[o] - mn[o]*sc[r];
        }
        float ps[4] = {0.f, 0.f, 0.f, 0.f};
#pragma unroll
        for (int fn = 0; fn < 4; ++fn) {
            int pg = wc*64 + fn*16 + lr;
            int p  = pt*128 + pg;
            float vv[4];
#pragma unroll
            for (int r = 0; r < 4; ++r) {
                float t = fmaf(acc[fm][fn][r], sc[r], sh[r]);
                vv[r] = t > 0.f ? t : 0.2f*t;
                ps[r] += vv[r];
            }
            uint2 u;
            u.x = (unsigned)bfb(vv[0]) | ((unsigned)bfb(vv[1]) << 16);
            u.y = (unsigned)bfb(vv[2]) | ((unsigned)bfb(vv[3]) << 16);
            *(uint2*)&ft[((size_t)n*HW_ + p)*C_ + obase] = u;
        }
        if (half) {
            // per-channel activation sums; 16 p-lanes share channels
#pragma unroll
            for (int r = 0; r < 4; ++r) {
                float s = ps[r];
                s += __shfl_xor(s, 1);
                s += __shfl_xor(s, 2);
                s += __shfl_xor(s, 4);
                s += __shfl_xor(s, 8);
                if (lr == 0) atomicAdd(&csum[n*C_ + obase + r], s);
            }
        }
    }
}

// ---------------------------------------------------------------------------
// MERGED Q/K + V GEMM in one 640-block launch. grid (16,10,4).
// XCD decode pins (n, p-parity); featT slice L2-resident (R10-verified).
// Q-half output scaled by log2(e) so flash attention can use exp2.
// ---------------------------------------------------------------------------
__global__ __launch_bounds__(256, 2) void k_gemm_qkv(
    const bf16s* __restrict__ Wqk, const bf16s* __restrict__ Wv,
    const bf16s* __restrict__ Bt,
    const float* __restrict__ bq, const float* __restrict__ bk,
    const float* __restrict__ bv,
    bf16s* __restrict__ qkb, bf16s* __restrict__ vb)
{
    __shared__ bf16s aL[64][36];
    __shared__ bf16s bL[256][36];
    const int tid = threadIdx.x;
    const int flat = blockIdx.x + (blockIdx.y << 4) + blockIdx.z * 160;
    const int k8 = flat & 7;
    const int n  = k8 >> 1;
    const int xh = k8 & 1;
    const int w8 = flat >> 3;                // 0..79
    const int yy = w8 % 10;
    const int p0 = ((((w8 / 10) << 1) | xh)) << 8;
    const bool isqk = (yy < 2);
    const int o0 = isqk ? yy*64 : (yy - 2)*64;
    const bf16s* A = isqk ? Wqk : Wv;
    const int lane = tid & 63;
    const int wid  = tid >> 6;
    const int lr = lane & 15, cb = lane >> 4;
    const int arow = tid >> 2, ach = (tid & 3) * 8;

    f32x4 acc[4][4];
#pragma unroll
    for (int i = 0; i < 4; ++i)
#pragma unroll
        for (int j = 0; j < 4; ++j) acc[i][j] = (f32x4){0.f,0.f,0.f,0.f};

    int4 pA, pB0, pB1, pB2, pB3;

#define GEMM_ISSUE(C0)                                                        \
    {                                                                         \
        pA = *(const int4*)&A[(size_t)(o0 + arow)*C_ + (C0) + ach];           \
        pB0 = *(const int4*)&Bt[((size_t)n*HW_ + p0 + arow      )*C_ + (C0) + ach]; \
        pB1 = *(const int4*)&Bt[((size_t)n*HW_ + p0 + arow +  64)*C_ + (C0) + ach]; \
        pB2 = *(const int4*)&Bt[((size_t)n*HW_ + p0 + arow + 128)*C_ + (C0) + ach]; \
        pB3 = *(const int4*)&Bt[((size_t)n*HW_ + p0 + arow + 192)*C_ + (C0) + ach]; \
    }

    GEMM_ISSUE(0)
    for (int c0 = 0; c0 < C_; c0 += 32) {
        *(int4*)&aL[arow][ach] = pA;
        *(int4*)&bL[arow      ][ach] = pB0;
        *(int4*)&bL[arow +  64][ach] = pB1;
        *(int4*)&bL[arow + 128][ach] = pB2;
        *(int4*)&bL[arow + 192][ach] = pB3;
        __syncthreads();
        if (c0 + 32 < C_) GEMM_ISSUE(c0 + 32)    // overlap with MFMA below
        bf16x8 af[4], bfv[4];
#pragma unroll
        for (int fo = 0; fo < 4; ++fo)
            af[fo] = *(const bf16x8*)&aL[fo*16 + lr][cb*8];
#pragma unroll
        for (int fp = 0; fp < 4; ++fp)
            bfv[fp] = *(const bf16x8*)&bL[wid*64 + fp*16 + lr][cb*8];
#pragma unroll
        for (int fo = 0; fo < 4; ++fo)
#pragma unroll
            for (int fp = 0; fp < 4; ++fp)
                acc[fo][fp] = __builtin_amdgcn_mfma_f32_16x16x32_bf16(
                    af[fo], bfv[fp], acc[fo][fp], 0, 0, 0);
        __syncthreads();
    }
#undef GEMM_ISSUE
#pragma unroll
    for (int fo = 0; fo < 4; ++fo) {
        const int obase = o0 + fo*16 + cb*4;
        const bool isq = isqk && !(obase >> 6);
        const float* bp = isqk ? ((obase >> 6) ? bk : bq) : bv;
        const int bofs = isqk ? (obase & 63) : obase;
        float bv4[4];
#pragma unroll
        for (int r = 0; r < 4; ++r) bv4[r] = bp[bofs + r];
#pragma unroll
        for (int fp = 0; fp < 4; ++fp) {
            int p = p0 + wid*64 + fp*16 + lr;
            float v[4];
#pragma unroll
            for (int r = 0; r < 4; ++r) {
                v[r] = acc[fo][fp][r] + bv4[r];
                if (isq) v[r] *= 1.44269504f;     // log2(e): pv uses exp2
            }
            if (isqk) {
                uint2 u;
                u.x = (unsigned)bfb(v[0]) | ((unsigned)bfb(v[1]) << 16);
                u.y = (unsigned)bfb(v[2]) | ((unsigned)bfb(v[3]) << 16);
                size_t base = (((size_t)((obase >> 6) * N_ + n))*HW_ + p)*64
                              + (obase & 63);
                *(uint2*)&qkb[base] = u;
            } else {
#pragma unroll
                for (int r = 0; r < 4; ++r)
                    vb[((size_t)(n*C_ + obase + r))*HW_ + p] =
                        __float2bfloat16(v[r]);
            }
        }
    }
}

// ---------------------------------------------------------------------------
// MERGED tail projections, cmlp FOLDED IN: one launch, grid (16,2,4).
// ---------------------------------------------------------------------------
__global__ __launch_bounds__(256, 2) void k_gemm_tail(
    const bf16s* __restrict__ Wpob, const bf16s* __restrict__ Wcob,
    const bf16s* __restrict__ featT, const bf16s* __restrict__ featT2,
    const float* __restrict__ b_pam, const float* __restrict__ b_cam,
    const float* __restrict__ s0, const float* __restrict__ Wc1,
    const float* __restrict__ bc1, const float* __restrict__ Wc2,
    const float* __restrict__ bc2,
    float* __restrict__ pam_low, float* __restrict__ cam_low)
{
    __shared__ bf16s aL[64][36];
    __shared__ bf16s bL[256][36];
    __shared__ float s2s[C_];
    __shared__ float s1s[CR_];
    const int tid = threadIdx.x;
    const int half = blockIdx.y;
    const int n  = blockIdx.z;
    const int p0 = blockIdx.x * 256;
    const bf16s* A = half ? Wcob : Wpob;
    const bf16s* Bt = half ? featT2 : featT;
    const float* bias = half ? b_cam : b_pam;
    float* outp = half ? cam_low : pam_low;
    const int lane = tid & 63;
    const int wid  = tid >> 6;
    const int lr = lane & 15, cb = lane >> 4;
    const int arow = tid >> 2, ach = (tid & 3) * 8;

    if (half) {                              // recompute s2 (CAM MLP) in-block
        if (tid < CR_) {
            float a = 0.f;
            for (int c = 0; c < C_; ++c)
                a = fmaf(Wc1[(size_t)tid*C_ + c], s0[n*C_ + c] * (1.f/HW_), a);
            a += bc1[tid];
            s1s[tid] = a > 0.f ? a : 0.2f*a;
        }
        __syncthreads();
        for (int c = tid; c < C_; c += 256) {
            float bb = 0.f;
            for (int i = 0; i < CR_; ++i)
                bb = fmaf(Wc2[(size_t)c*CR_ + i], s1s[i], bb);
            bb += bc2[c];
            s2s[c] = 1.f / (1.f + __expf(-bb));
        }
        __syncthreads();
    }

    f32x4 acc[4][4];
#pragma unroll
    for (int i = 0; i < 4; ++i)
#pragma unroll
        for (int j = 0; j < 4; ++j) acc[i][j] = (f32x4){0.f,0.f,0.f,0.f};

    int4 pA, pB0, pB1, pB2, pB3;

#define GEMM_ISSUE(C0)                                                        \
    {                                                                         \
        pA = *(const int4*)&A[(size_t)arow*C_ + (C0) + ach];                  \
        pB0 = *(const int4*)&Bt[((size_t)n*HW_ + p0 + arow      )*C_ + (C0) + ach]; \
        pB1 = *(const int4*)&Bt[((size_t)n*HW_ + p0 + arow +  64)*C_ + (C0) + ach]; \
        pB2 = *(const int4*)&Bt[((size_t)n*HW_ + p0 + arow + 128)*C_ + (C0) + ach]; \
        pB3 = *(const int4*)&Bt[((size_t)n*HW_ + p0 + arow + 192)*C_ + (C0) + ach]; \
    }

    GEMM_ISSUE(0)
    for (int c0 = 0; c0 < C_; c0 += 32) {
        if (half) {
            const bf16s* sp = (const bf16s*)&pA;
            bf16s tmp[8];
#pragma unroll
            for (int u = 0; u < 8; ++u)
                tmp[u] = __float2bfloat16(
                    __bfloat162float(sp[u]) * s2s[c0 + ach + u]);
            *(int4*)&aL[arow][ach] = *(int4*)tmp;
        } else {
            *(int4*)&aL[arow][ach] = pA;
        }
        *(int4*)&bL[arow      ][ach] = pB0;
        *(int4*)&bL[arow +  64][ach] = pB1;
        *(int4*)&bL[arow + 128][ach] = pB2;
        *(int4*)&bL[arow + 192][ach] = pB3;
        __syncthreads();
        if (c0 + 32 < C_) GEMM_ISSUE(c0 + 32)    // overlap with MFMA below
        bf16x8 af[4], bfv[4];
#pragma unroll
        for (int fo = 0; fo < 4; ++fo)
            af[fo] = *(const bf16x8*)&aL[fo*16 + lr][cb*8];
#pragma unroll
        for (int fp = 0; fp < 4; ++fp)
            bfv[fp] = *(const bf16x8*)&bL[wid*64 + fp*16 + lr][cb*8];
#pragma unroll
        for (int fo = 0; fo < 4; ++fo)
#pragma unroll
            for (int fp = 0; fp < 4; ++fp)
                acc[fo][fp] = __builtin_amdgcn_mfma_f32_16x16x32_bf16(
                    af[fo], bfv[fp], acc[fo][fp], 0, 0, 0);
        __syncthreads();
    }
#undef GEMM_ISSUE
#pragma unroll
    for (int fo = 0; fo < 4; ++fo) {
        const int obase = fo*16 + cb*4;
        float bv[4];
#pragma unroll
        for (int r = 0; r < 4; ++r) bv[r] = bias[obase + r];
#pragma unroll
        for (int fp = 0; fp < 4; ++fp) {
            int p = p0 + wid*64 + fp*16 + lr;
#pragma unroll
            for (int r = 0; r < 4; ++r)
                outp[((size_t)(n*NC_ + obase + r))*HW_ + p] =
                    acc[fo][fp][r] + bv[r];
        }
    }
}

// ---------------------------------------------------------------------------
// pass B, FULL FLASH (R13-verified, R14 +setprio, R17 exp2+defer-max).
// ---------------------------------------------------------------------------
__global__ __launch_bounds__(256, 4) void k_pv_mfma(
    const bf16s* __restrict__ qb, const bf16s* __restrict__ kb,
    const bf16s* __restrict__ vb, const float* __restrict__ alpha,
    bf16s* __restrict__ featT)
{
    __shared__ bf16s ks[2][4096];
    __shared__ bf16s ps[2][4096];
    __shared__ float sfl[2][64];                 // per-column rescale factors
    __shared__ float lfin[64];                   // final denominators
    const int tid = threadIdx.x;
    const int lid = blockIdx.x + (blockIdx.y << 6) + (blockIdx.z << 8);
    const int k8  = lid & 7;
    const int n   = k8 >> 1;
    const int cc0 = (((lid >> 3) & 1) * 2 + (k8 & 1)) << 7;   // {0,128,256,384}
    const int i0  = (lid >> 4) << 6;
    const int lane = tid & 63;
    const int wid  = tid >> 6;
    const int lr = lane & 15, cb = lane >> 4;

    // stage Q into ks[0] (overwritten with K(0) after frag read)
    for (int e = tid; e < 512; e += 256) {
        int row = e >> 3, ch = e & 7;
        *(int4*)&ks[0][swz8(row, ch)] =
            *(const int4*)&qb[((size_t)n*HW_ + i0 + row)*CR_ + ch*8];
    }
    const int krow = tid >> 3, kch = tid & 7;
    const bf16s* kbase = kb + (size_t)n*HW_*CR_ + kch*8;
    int4 kreg0 = *(const int4*)(kbase + (size_t)krow*CR_);
    int4 kreg1 = *(const int4*)(kbase + (size_t)(krow + 32)*CR_);
    __syncthreads();                             // Q visible
    bf16x8 bq[2];                                // loop-invariant Q fragments
#pragma unroll
    for (int kk = 0; kk < 2; ++kk)
        bq[kk] = *(const bf16x8*)&ks[0][swz8(wid*16 + lr, kk*4 + cb)];

    const float al = alpha[0];
    __syncthreads();                             // Q frag reads done
    *(int4*)&ks[0][swz8(krow, kch)] = kreg0;     // commit K(0)
    *(int4*)&ks[0][swz8(krow + 32, kch)] = kreg1;
    kreg0 = *(const int4*)(kbase + (size_t)(64 + krow)*CR_);       // K(1)
    kreg1 = *(const int4*)(kbase + (size_t)(64 + krow + 32)*CR_);
    __syncthreads();                             // ks[0]=K(0) visible

    f32x4 acc[2][4];                             // [fc2][fi]
#pragma unroll
    for (int i = 0; i < 2; ++i)
#pragma unroll
        for (int j = 0; j < 4; ++j) acc[i][j] = (f32x4){0.f,0.f,0.f,0.f};

    float m_run = -INFINITY, l_run = 0.f;        // stats for column i0+wid*16+lr

    const bf16s* vbase = vb + ((size_t)(n*C_ + cc0 + wid*32))*HW_;
    bf16x8 vc0, vc1, vc2, vc3, vn0, vn1, vn2, vn3;

    for (int jt = 0; jt < 64; ++jt) {
        // 1. issue V(jt) loads (independent; consumed next iteration)
        const bf16s* vj = vbase + jt*64;
        vn0 = *(const bf16x8*)(vj + (size_t)(     lr)*HW_      + cb*8);
        vn1 = *(const bf16x8*)(vj + (size_t)(16 + lr)*HW_      + cb*8);
        vn2 = *(const bf16x8*)(vj + (size_t)(     lr)*HW_ + 32 + cb*8);
        vn3 = *(const bf16x8*)(vj + (size_t)(16 + lr)*HW_ + 32 + cb*8);
        // 2. PV(jt-1): rescale acc by f(jt-1), then MFMA on ps[(jt-1)&1]
        if (jt > 0) {
            const float* fs = sfl[(jt - 1) & 1];
            const bf16s* pp = ps[(jt - 1) & 1];
            bf16x8 pa[4];
#pragma unroll
            for (int fi = 0; fi < 4; ++fi) {
                const float f = fs[fi*16 + lr];
#pragma unroll
                for (int r = 0; r < 4; ++r) {
                    acc[0][fi][r] *= f;
                    acc[1][fi][r] *= f;
                }
            }
#pragma unroll
            for (int fi = 0; fi < 4; ++fi)
                pa[fi] = *(const bf16x8*)&pp[swz8(fi*16 + lr, cb)];
            __builtin_amdgcn_s_setprio(1);
#pragma unroll
            for (int fi = 0; fi < 4; ++fi) {
                acc[0][fi] = __builtin_amdgcn_mfma_f32_16x16x32_bf16(
                    vc0, pa[fi], acc[0][fi], 0, 0, 0);
                acc[1][fi] = __builtin_amdgcn_mfma_f32_16x16x32_bf16(
                    vc1, pa[fi], acc[1][fi], 0, 0, 0);
            }
            __builtin_amdgcn_s_setprio(0);
#pragma unroll
            for (int fi = 0; fi < 4; ++fi)
                pa[fi] = *(const bf16x8*)&pp[swz8(fi*16 + lr, 4 + cb)];
            __builtin_amdgcn_s_setprio(1);
#pragma unroll
            for (int fi = 0; fi < 4; ++fi) {
                acc[0][fi] = __builtin_amdgcn_mfma_f32_16x16x32_bf16(
                    vc2, pa[fi], acc[0][fi], 0, 0, 0);
                acc[1][fi] = __builtin_amdgcn_mfma_f32_16x16x32_bf16(
                    vc3, pa[fi], acc[1][fi], 0, 0, 0);
            }
            __builtin_amdgcn_s_setprio(0);
        }
        // 3. S^T(jt) from ks[jt&1]; online column stats (log2 domain);
        //    P = exp2(s - m_run) -> ps[jt&1]
        {
            const bf16s* kst = ks[jt & 1];
            bf16s* pst = ps[jt & 1];
            f32x4 sv0 = (f32x4){0.f,0.f,0.f,0.f};
            f32x4 sv1 = (f32x4){0.f,0.f,0.f,0.f};
            f32x4 sv2 = (f32x4){0.f,0.f,0.f,0.f};
            f32x4 sv3 = (f32x4){0.f,0.f,0.f,0.f};
            sv0 = __builtin_amdgcn_mfma_f32_16x16x32_bf16(
                *(const bf16x8*)&kst[swz8(     lr, cb)], bq[0], sv0, 0, 0, 0);
            sv0 = __builtin_amdgcn_mfma_f32_16x16x32_bf16(
                *(const bf16x8*)&kst[swz8(     lr, 4 + cb)], bq[1], sv0, 0, 0, 0);
            sv1 = __builtin_amdgcn_mfma_f32_16x16x32_bf16(
                *(const bf16x8*)&kst[swz8(16 + lr, cb)], bq[0], sv1, 0, 0, 0);
            sv1 = __builtin_amdgcn_mfma_f32_16x16x32_bf16(
                *(const bf16x8*)&kst[swz8(16 + lr, 4 + cb)], bq[1], sv1, 0, 0, 0);
            sv2 = __builtin_amdgcn_mfma_f32_16x16x32_bf16(
                *(const bf16x8*)&kst[swz8(32 + lr, cb)], bq[0], sv2, 0, 0, 0);
            sv2 = __builtin_amdgcn_mfma_f32_16x16x32_bf16(
                *(const bf16x8*)&kst[swz8(32 + lr, 4 + cb)], bq[1], sv2, 0, 0, 0);
            sv3 = __builtin_amdgcn_mfma_f32_16x16x32_bf16(
                *(const bf16x8*)&kst[swz8(48 + lr, cb)], bq[0], sv3, 0, 0, 0);
            sv3 = __builtin_amdgcn_mfma_f32_16x16x32_bf16(
                *(const bf16x8*)&kst[swz8(48 + lr, 4 + cb)], bq[1], sv3, 0, 0, 0);
            // column max over this thread's 16 j's, then over cb group
            float tmax = sv0[0];
#pragma unroll
            for (int r = 0; r < 4; ++r) {
                tmax = fmaxf(tmax, sv0[r]); tmax = fmaxf(tmax, sv1[r]);
                tmax = fmaxf(tmax, sv2[r]); tmax = fmaxf(tmax, sv3[r]);
            }
            tmax = fmaxf(tmax, __shfl_xor(tmax, 16));
            tmax = fmaxf(tmax, __shfl_xor(tmax, 32));
            float fsc;
            if (tmax > m_run + 11.5f) {          // T13 defer-max (8 nats)
                fsc = ex2(m_run - tmax);         // 0 on first tile
                m_run = tmax;
            } else {
                fsc = 1.f;
            }
            float tsum = 0.f;
#define PV_PACK(SV, FJ)                                                       \
            {                                                                 \
                float p0_ = ex2(SV[0] - m_run), p1_ = ex2(SV[1] - m_run);     \
                float p2_ = ex2(SV[2] - m_run), p3_ = ex2(SV[3] - m_run);     \
                tsum += (p0_ + p1_) + (p2_ + p3_);                            \
                uint2 u;                                                      \
                u.x = (unsigned)bfb(p0_) | ((unsigned)bfb(p1_) << 16);        \
                u.y = (unsigned)bfb(p2_) | ((unsigned)bfb(p3_) << 16);        \
                *(uint2*)&pst[swz8(wid*16 + lr, FJ*2 + (cb >> 1)) + (cb & 1)*4] = u; \
            }
            PV_PACK(sv0, 0)
            PV_PACK(sv1, 1)
            PV_PACK(sv2, 2)
            PV_PACK(sv3, 3)
#undef PV_PACK
            tsum += __shfl_xor(tsum, 16);
            tsum += __shfl_xor(tsum, 32);
            l_run = l_run * fsc + tsum;
            if (cb == 0) sfl[jt & 1][wid*16 + lr] = fsc;
        }
        // 4. commit K(jt+1), prefetch K(jt+2)
        if (jt < 63) {
            *(int4*)&ks[(jt + 1) & 1][swz8(krow, kch)] = kreg0;
            *(int4*)&ks[(jt + 1) & 1][swz8(krow + 32, kch)] = kreg1;
            if (jt < 62) {
                kreg0 = *(const int4*)(kbase + (size_t)((jt+2)*64 + krow)*CR_);
                kreg1 = *(const int4*)(kbase + (size_t)((jt+2)*64 + krow + 32)*CR_);
            }
        }
        // 5. rotate V regs
        vc0 = vn0; vc1 = vn1; vc2 = vn2; vc3 = vn3;
        __syncthreads();                         // ps/sfl(jt) visible
    }
    // publish final denominators
    if (cb == 0) lfin[wid*16 + lr] = l_run;
    // epilogue PV(63): rescale by f(63) then MFMA
    {
        const float* fs = sfl[1];
        const bf16s* pp = ps[1];
        bf16x8 pa[4];
#pragma unroll
        for (int fi = 0; fi < 4; ++fi) {
            const float f = fs[fi*16 + lr];
#pragma unroll
            for (int r = 0; r < 4; ++r) {
                acc[0][fi][r] *= f;
                acc[1][fi][r] *= f;
            }
        }
#pragma unroll
        for (int fi = 0; fi < 4; ++fi)
            pa[fi] = *(const bf16x8*)&pp[swz8(fi*16 + lr, cb)];
#pragma unroll
        for (int fi = 0; fi < 4; ++fi) {
            acc[0][fi] = __builtin_amdgcn_mfma_f32_16x16x32_bf16(
                vc0, pa[fi], acc[0][fi], 0, 0, 0);
            acc[1][fi] = __builtin_amdgcn_mfma_f32_16x16x32_bf16(
                vc1, pa[fi], acc[1][fi], 0, 0, 0);
        }
#pragma unroll
        for (int fi = 0; fi < 4; ++fi)
            pa[fi] = *(const bf16x8*)&pp[swz8(fi*16 + lr, 4 + cb)];
#pragma unroll
        for (int fi = 0; fi < 4; ++fi) {
            acc[0][fi] = __builtin_amdgcn_mfma_f32_16x16x32_bf16(
                vc2, pa[fi], acc[0][fi], 0, 0, 0);
            acc[1][fi] = __builtin_amdgcn_mfma_f32_16x16x32_bf16(
                vc3, pa[fi], acc[1][fi], 0, 0, 0);
        }
    }
    __syncthreads();                             // lfin visible
    // epilogue: normalize + residual add (bf16 featT RMW) + uint2 stores
#pragma unroll
    for (int fc2 = 0; fc2 < 2; ++fc2) {
        const int ccl = wid*32 + fc2*16 + cb*4;
#pragma unroll
        for (int fi = 0; fi < 4; ++fi) {
            const int p = i0 + fi*16 + lr;
            const float rv = al / lfin[fi*16 + lr];
            bf16s* fb = &featT[((size_t)n*HW_ + p)*C_ + cc0 + ccl];
            uint2 fv = *(const uint2*)fb;
            float f0 = b2f((unsigned short)(fv.x & 0xffff));
            float f1 = b2f((unsigned short)(fv.x >> 16));
            float f2 = b2f((unsigned short)(fv.y & 0xffff));
            float f3 = b2f((unsigned short)(fv.y >> 16));
            float v0 = fmaf(rv, acc[fc2][fi][0], f0);
            float v1 = fmaf(rv, acc[fc2][fi][1], f1);
            float v2 = fmaf(rv, acc[fc2][fi][2], f2);
            float v3 = fmaf(rv, acc[fc2][fi][3], f3);
            uint2 u;
            u.x = (unsigned)bfb(v0) | ((unsigned)bfb(v1) << 16);
            u.y = (unsigned)bfb(v2) | ((unsigned)bfb(v3) << 16);
            *(uint2*)fb = u;
        }
    }
}

// ---------------------------------------------------------------------------
__global__ __launch_bounds__(256) void k_up(
    const float* __restrict__ pl, const float* __restrict__ cl,
    float* __restrict__ out)
{
    int idx = blockIdx.x * 256 + threadIdx.x;
    int ox = idx & 127; int rest = idx >> 7;
    int oy = rest & 127; rest >>= 7;
    int o  = rest & 63;  int n = rest >> 6;
    float fy = oy*0.5f - 0.25f;
    float fx = ox*0.5f - 0.25f;
    int y0 = (int)floorf(fy); float wy = fy - y0;
    int x0 = (int)floorf(fx); float wx = fx - x0;
    int y0c = y0 < 0 ? 0 : y0;      int y1c = y0+1 > 63 ? 63 : y0+1;
    int x0c = x0 < 0 ? 0 : x0;      int x1c = x0+1 > 63 ? 63 : x0+1;
    const float* a = pl + ((size_t)(n*NC_ + o))*HW_;
    const float* b = cl + ((size_t)(n*NC_ + o))*HW_;
    float v00 = a[y0c*64+x0c] + b[y0c*64+x0c];
    float v01 = a[y0c*64+x1c] + b[y0c*64+x1c];
    float v10 = a[y1c*64+x0c] + b[y1c*64+x0c];
    float v11 = a[y1c*64+x1c] + b[y1c*64+x1c];
    out[idx] = (1.f-wy)*((1.f-wx)*v00 + wx*v01) + wy*((1.f-wx)*v10 + wx*v11);
}

// ---------------------------------------------------------------------------
extern "C" void kernel_launch(void* const* d_in, const int* in_sizes, int n_in,
                              void* d_out, int out_size, void* d_ws, size_t ws_size,
                              hipStream_t stream)
{
    const float* x         = (const float*)d_in[0];
    const float* W_pam_in  = (const float*)d_in[1];
    const float* pam_g     = (const float*)d_in[2];
    const float* pam_b     = (const float*)d_in[3];
    const float* pam_m     = (const float*)d_in[4];
    const float* pam_v     = (const float*)d_in[5];
    const float* Wq        = (const float*)d_in[6];
    const float* bq        = (const float*)d_in[7];
    const float* Wk        = (const float*)d_in[8];
    const float* bk        = (const float*)d_in[9];
    const float* Wv        = (const float*)d_in[10];
    const float* bv        = (const float*)d_in[11];
    const float* alpha     = (const float*)d_in[12];
    const float* W_pam_out = (const float*)d_in[13];
    const float* b_pam_out = (const float*)d_in[14];
    const float* W_cam_in  = (const float*)d_in[15];
    const float* cam_g     = (const float*)d_in[16];
    const float* cam_b     = (const float*)d_in[17];
    const float* cam_m     = (const float*)d_in[18];
    const float* cam_v     = (const float*)d_in[19];
    const float* Wc1       = (const float*)d_in[20];
    const float* bc1       = (const float*)d_in[21];
    const float* Wc2       = (const float*)d_in[22];
    const float* bc2       = (const float*)d_in[23];
    const float* W_cam_out = (const float*)d_in[24];
    const float* b_cam_out = (const float*)d_in[25];

    float* pam_low = (float*)d_ws;             // [4][64][4096]
    float* s0      = pam_low + 1048576;        // [4][512]
    bf16s* xbT     = (bf16s*)(s0 + 2048);      // [4][4096][512] bf16
    bf16s* featTb  = xbT + 8388608;            // [4][4096][512] (PAM)
    bf16s* featTb2 = featTb + 8388608;         // [4][4096][512] (CAM)
    bf16s* vb      = featTb2 + 8388608;        // [4][512][4096]
    bf16s* qb      = vb + 8388608;             // [4][4096][64]
    bf16s* kb      = qb + 1048576;             // adjacent to qb (qkv fuse)
    bf16s* wbp     = kb + 1048576;             // [512][9][512] PAM
    bf16s* wbp2    = wbp + 2359296;            // [512][9][512] CAM
    bf16s* Wqb     = wbp2 + 2359296;           // [64][512]
    bf16s* Wkb     = Wqb + 32768;              // adjacent to Wqb (concat A)
    bf16s* Wvb     = Wkb + 32768;              // [512][512]
    bf16s* Wpob    = Wvb + 262144;             // [64][512]
    bf16s* Wcob    = Wpob + 32768;             // [64][512]
    float* cam_low = (float*)qb;               // aliases qb+kb (dead after pv)

    dim3 b256(256);
    // merged prologue: weight prep + s0 zero + x transpose, one launch
    k_prep<<<dim3(22024), b256, 0, stream>>>(
        x, W_pam_in, W_cam_in, Wq, Wk, Wv, W_pam_out, W_cam_out,
        xbT, wbp, wbp2, Wqb, Wkb, Wvb, Wpob, Wcob, s0);
    // merged PAM+CAM conv: direct-A, 4-row B stage, 2 barriers/c0
    k_conv3x3_mfma<<<dim3(32,8,4), b256, 0, stream>>>(
        xbT, wbp, wbp2, pam_g, pam_b, pam_m, pam_v,
        cam_g, cam_b, cam_m, cam_v, featTb, featTb2, s0);
    // merged Q+K+V gemm, XCD-swizzled (Q scaled by log2e for exp2 flash)
    k_gemm_qkv<<<dim3(16,10,4), b256, 0, stream>>>(
        Wqb, Wvb, featTb, bq, bk, bv, qb, vb);
    // flash attention (exp2 domain, T13 defer-max)
    k_pv_mfma<<<dim3(64,4,4), b256, 0, stream>>>(
        qb, kb, vb, alpha, featTb);
    // merged tail projections with cmlp folded in (128 blocks)
    k_gemm_tail<<<dim3(16,2,4), b256, 0, stream>>>(
        Wpob, Wcob, featTb, featTb2, b_pam_out, b_cam_out,
        s0, Wc1, bc1, Wc2, bc2, pam_low, cam_low);
    // upsample + add
    k_up<<<dim3(16384), b256, 0, stream>>>(pam_low, cam_low, (float*)d_out);
}

// Round 19
// 406.071 us; speedup vs baseline: 1.6178x; 1.6178x over previous
//
#include <hip/hip_runtime.h>
#include <hip/hip_bf16.h>
#include <math.h>

#define N_  4
#define C_  512
#define H_  64
#define W_  64
#define HW_ 4096
#define CR_ 64
#define NC_ 64
#define EPSV 1e-5f

typedef __attribute__((ext_vector_type(8))) __bf16 bf16x8;
typedef __attribute__((ext_vector_type(4))) float f32x4;
typedef __hip_bfloat16 bf16s;

__device__ __forceinline__ unsigned short bfb(float f) {
    union { bf16s h; unsigned short u; } cv;
    cv.h = __float2bfloat16(f);
    return cv.u;
}

__device__ __forceinline__ float b2f(unsigned short h) {
    union { unsigned u; float f; } c; c.u = ((unsigned)h) << 16; return c.f;
}

__device__ __forceinline__ float ex2(float x) {
    return __builtin_amdgcn_exp2f(x);        // raw v_exp_f32
}

// XOR-swizzled element offset for a [64][64] bf16 LDS tile (128 B rows,
// 8 chunks of 16 B). chunk' = chunk ^ (row&7) -> conflict-free b128 access.
__device__ __forceinline__ int swz8(int row, int ch) {
    return row * 64 + ((ch ^ (row & 7)) << 3);
}

// ---------------------------------------------------------------------------
// MERGED prologue: weight transposes + bf16 casts + s0 zero + x transpose
// in ONE launch. Blocks < 19976: flat elementwise segments. Blocks >= 19976:
// 64x64 x-transpose tiles (whole-block branch).
// ---------------------------------------------------------------------------
__global__ __launch_bounds__(256) void k_prep(
    const float* __restrict__ x,
    const float* __restrict__ Wpam, const float* __restrict__ Wcam,
    const float* __restrict__ Wq, const float* __restrict__ Wk,
    const float* __restrict__ Wv, const float* __restrict__ Wpo,
    const float* __restrict__ Wco,
    bf16s* __restrict__ xbT,
    bf16s* __restrict__ wbp, bf16s* __restrict__ wbp2,
    bf16s* __restrict__ Wqb, bf16s* __restrict__ Wkb,
    bf16s* __restrict__ Wvb, bf16s* __restrict__ Wpob,
    bf16s* __restrict__ Wcob, float* __restrict__ s0)
{
    __shared__ float xs[64][65];
    const int b = blockIdx.x;
    if (b >= 19976) {                        // x-transpose tile
        const int idx = b - 19976;           // 0..2047
        const int n   = idx >> 9;
        const int rem = idx & 511;
        const int p0  = (rem & 63) * 64;
        const int c0  = (rem >> 6) * 64;
        const int tid = threadIdx.x;
        for (int e = tid; e < 4096; e += 256) {
            int ci = e >> 6, pi = e & 63;
            xs[ci][pi] = x[((size_t)(n*C_ + c0 + ci))*HW_ + p0 + pi];
        }
        __syncthreads();
        for (int e = tid; e < 4096; e += 256) {
            int pi = e >> 6, ci = e & 63;
            xbT[((size_t)n*HW_ + p0 + pi)*C_ + c0 + ci] =
                __float2bfloat16(xs[ci][pi]);
        }
        return;
    }
    long e = (long)b * 256 + threadIdx.x;
    if (e < 2359296) {
        int c = e & 511; int r = e >> 9;
        int tap = r % 9; int o = r / 9;
        wbp[e] = __float2bfloat16(Wpam[((size_t)o*C_ + c)*9 + tap]);
        return;
    }
    e -= 2359296;
    if (e < 2359296) {
        int c = e & 511; int r = e >> 9;
        int tap = r % 9; int o = r / 9;
        wbp2[e] = __float2bfloat16(Wcam[((size_t)o*C_ + c)*9 + tap]);
        return;
    }
    e -= 2359296;
    if (e < 32768) { Wqb[e] = __float2bfloat16(Wq[e]); return; }
    e -= 32768;
    if (e < 32768) { Wkb[e] = __float2bfloat16(Wk[e]); return; }
    e -= 32768;
    if (e < 262144) { Wvb[e] = __float2bfloat16(Wv[e]); return; }
    e -= 262144;
    if (e < 32768) { Wpob[e] = __float2bfloat16(Wpo[e]); return; }
    e -= 32768;
    if (e < 32768) { Wcob[e] = __float2bfloat16(Wco[e]); return; }
    e -= 32768;
    if (e < 2048) s0[e] = 0.f;
}

// ---------------------------------------------------------------------------
// MERGED conv3x3 + BN + LReLU implicit-GEMM MFMA, PAM+CAM in one launch.
// R10-VERIFIED (194 us): single-buffer LDS 37.4 KB (~3 blk/CU), 2 barriers,
// stride-36 rows, XCD-swizzled decode. (R18's direct-A regressed 2.5x —
// wave-shared MFMA operands must live in LDS; thrice-confirmed.)
// ---------------------------------------------------------------------------
__global__ __launch_bounds__(256, 3) void k_conv3x3_mfma(
    const bf16s* __restrict__ xbT,
    const bf16s* __restrict__ wb,  const bf16s* __restrict__ wb2,
    const float* __restrict__ gamma,  const float* __restrict__ beta,
    const float* __restrict__ mean,   const float* __restrict__ var,
    const float* __restrict__ gamma2, const float* __restrict__ beta2,
    const float* __restrict__ mean2,  const float* __restrict__ var2,
    bf16s* __restrict__ featT, bf16s* __restrict__ featT2,
    float* __restrict__ csum)
{
    __shared__ bf16s aL[3][128][36];
    __shared__ bf16s bL[132][36];            // [ry*66+xi][ch]
    const int tid = threadIdx.x;
    const int lid = blockIdx.x + (blockIdx.y << 5) + (blockIdx.z << 8);
    const int xcd = lid & 7;                 // XCD pin: (half, n) fixed per XCD
    const int half = xcd >> 2;               // 0=PAM, 1=CAM
    const int n    = xcd & 3;
    const int w8   = lid >> 3;               // 0..127
    const int o0 = (w8 >> 5) * 128;          // o-quarter: 32 consecutive blocks
    const int pt = w8 & 31;                  //   share one weight panel
    const int y0 = pt * 2;
    const bf16s* wbs = half ? wb2 : wb;
    const float* gm = half ? gamma2 : gamma;
    const float* bt = half ? beta2  : beta;
    const float* mn = half ? mean2  : mean;
    const float* vr = half ? var2   : var;
    bf16s* ft = half ? featT2 : featT;
    const int lane = tid & 63;
    const int wid  = tid >> 6;
    const int wr = wid >> 1, wc = wid & 1;
    const int lr = lane & 15, cb = lane >> 4;

    // per-thread staging coordinates (constant across iterations)
    const int ao  = tid >> 2;                // A row within half
    const int ac  = (tid & 3) * 8;           // chunk offset (elems)
    const int t0  = tid >> 2;                // B token k=0 (ry=0, xi=t0)
    const int t1  = t0 + 64;                 // B token k=1
    const int t2  = t0 + 128;                // B token k=2 (valid if tid<16)
    const int ry1 = t1 >= 66 ? 1 : 0;
    const int xi1 = t1 - (ry1 ? 66 : 0);

    f32x4 acc[4][4];
#pragma unroll
    for (int i = 0; i < 4; ++i)
#pragma unroll
        for (int j = 0; j < 4; ++j) acc[i][j] = (f32x4){0.f,0.f,0.f,0.f};

    int4 pA0, pA1, pA2, pA3, pA4, pA5, pB0, pB1, pB2;

#define CONV_AADDR(DXI, OHALF, C0, DYI) \
    (const int4*)(wbs + ((size_t)(o0 + (OHALF) + ao)*9 + (DYI)*3 + (DXI))*C_ + (C0) + ac)

#define CONV_BLOAD(DST, RY, XI, C0, DYI, VALID)                               \
    {                                                                         \
        int row_ = y0 + (DYI) - 1 + (RY);                                     \
        int xc_  = (XI) - 1;                                                  \
        int4 v_ = {0,0,0,0};                                                  \
        if ((VALID) && row_ >= 0 && row_ < H_ && xc_ >= 0 && xc_ < W_)        \
            v_ = *(const int4*)(xbT +                                         \
                ((size_t)n*HW_ + row_*W_ + xc_)*C_ + (C0) + ac);              \
        DST = v_;                                                             \
    }

#define CONV_ISSUE(C0, DYI)                                                   \
    {                                                                         \
        pA0 = *CONV_AADDR(0,  0, C0, DYI);                                    \
        pA1 = *CONV_AADDR(0, 64, C0, DYI);                                    \
        pA2 = *CONV_AADDR(1,  0, C0, DYI);                                    \
        pA3 = *CONV_AADDR(1, 64, C0, DYI);                                    \
        pA4 = *CONV_AADDR(2,  0, C0, DYI);                                    \
        pA5 = *CONV_AADDR(2, 64, C0, DYI);                                    \
        CONV_BLOAD(pB0, 0, t0, C0, DYI, 1)                                    \
        CONV_BLOAD(pB1, ry1, xi1, C0, DYI, 1)                                 \
        CONV_BLOAD(pB2, 1, t2 - 66, C0, DYI, tid < 16)                        \
    }

    CONV_ISSUE(0, 0)
    int c0 = 0, dyi = 0;
    for (int it = 0; it < 48; ++it) {
        // commit prefetched regs -> LDS (compiler inserts the vmcnt wait)
        *(int4*)&aL[0][ao][ac]      = pA0;
        *(int4*)&aL[0][64 + ao][ac] = pA1;
        *(int4*)&aL[1][ao][ac]      = pA2;
        *(int4*)&aL[1][64 + ao][ac] = pA3;
        *(int4*)&aL[2][ao][ac]      = pA4;
        *(int4*)&aL[2][64 + ao][ac] = pA5;
        *(int4*)&bL[t0][ac] = pB0;
        *(int4*)&bL[t1][ac] = pB1;
        if (tid < 16) *(int4*)&bL[t2][ac] = pB2;
        __syncthreads();                     // tiles(it) visible
        int nd = dyi + 1, nc = c0;
        if (nd == 3) { nd = 0; nc += 32; }
        if (it < 47) CONV_ISSUE(nc, nd)      // overlap with MFMA below
#pragma unroll
        for (int dxi = 0; dxi < 3; ++dxi) {
            bf16x8 af[4], bfv[4];
#pragma unroll
            for (int fm = 0; fm < 4; ++fm)
                af[fm] = *(const bf16x8*)&aL[dxi][wr*64 + fm*16 + lr][cb*8];
#pragma unroll
            for (int fn = 0; fn < 4; ++fn) {
                int pg = wc*64 + fn*16 + lr;
                int ry = pg >> 6, xc = pg & 63;
                bfv[fn] = *(const bf16x8*)&bL[ry*66 + xc + dxi][cb*8];
            }
#pragma unroll
            for (int fm = 0; fm < 4; ++fm)
#pragma unroll
                for (int fn = 0; fn < 4; ++fn)
                    acc[fm][fn] = __builtin_amdgcn_mfma_f32_16x16x32_bf16(
                        af[fm], bfv[fn], acc[fm][fn], 0, 0, 0);
        }
        __syncthreads();                     // readers(it) done
        c0 = nc; dyi = nd;
    }
#undef CONV_ISSUE
#undef CONV_BLOAD
#undef CONV_AADDR
#pragma unroll
    for (int fm = 0; fm < 4; ++fm) {
        float sc[4], sh[4];
        const int obase = o0 + wr*64 + fm*16 + cb*4;
#pragma unroll
        for (int r = 0; r < 4; ++r) {
            int o = obase + r;
            sc[r] = gm[o] * rsqrtf(vr[o] + EPSV);
            sh[r] = bt[o] - mn[o]*sc[r];
        }
        float ps[4] = {0.f, 0.f, 0.f, 0.f};
#pragma unroll
        for (int fn = 0; fn < 4; ++fn) {
            int pg = wc*64 + fn*16 + lr;
            int p  = pt*128 + pg;
            float vv[4];
#pragma unroll
            for (int r = 0; r < 4; ++r) {
                float t = fmaf(acc[fm][fn][r], sc[r], sh[r]);
                vv[r] = t > 0.f ? t : 0.2f*t;
                ps[r] += vv[r];
            }
            uint2 u;
            u.x = (unsigned)bfb(vv[0]) | ((unsigned)bfb(vv[1]) << 16);
            u.y = (unsigned)bfb(vv[2]) | ((unsigned)bfb(vv[3]) << 16);
            *(uint2*)&ft[((size_t)n*HW_ + p)*C_ + obase] = u;
        }
        if (half) {
            // per-channel activation sums; 16 p-lanes share channels
#pragma unroll
            for (int r = 0; r < 4; ++r) {
                float s = ps[r];
                s += __shfl_xor(s, 1);
                s += __shfl_xor(s, 2);
                s += __shfl_xor(s, 4);
                s += __shfl_xor(s, 8);
                if (lr == 0) atomicAdd(&csum[n*C_ + obase + r], s);
            }
        }
    }
}

// ---------------------------------------------------------------------------
// MERGED Q/K + V GEMM in one 640-block launch. grid (16,10,4).
// XCD decode pins (n, p-parity); featT slice L2-resident (R10-verified).
// Q-half output scaled by log2(e) so flash attention can use exp2.
// ---------------------------------------------------------------------------
__global__ __launch_bounds__(256, 2) void k_gemm_qkv(
    const bf16s* __restrict__ Wqk, const bf16s* __restrict__ Wv,
    const bf16s* __restrict__ Bt,
    const float* __restrict__ bq, const float* __restrict__ bk,
    const float* __restrict__ bv,
    bf16s* __restrict__ qkb, bf16s* __restrict__ vb)
{
    __shared__ bf16s aL[64][36];
    __shared__ bf16s bL[256][36];
    const int tid = threadIdx.x;
    const int flat = blockIdx.x + (blockIdx.y << 4) + blockIdx.z * 160;
    const int k8 = flat & 7;
    const int n  = k8 >> 1;
    const int xh = k8 & 1;
    const int w8 = flat >> 3;                // 0..79
    const int yy = w8 % 10;
    const int p0 = ((((w8 / 10) << 1) | xh)) << 8;
    const bool isqk = (yy < 2);
    const int o0 = isqk ? yy*64 : (yy - 2)*64;
    const bf16s* A = isqk ? Wqk : Wv;
    const int lane = tid & 63;
    const int wid  = tid >> 6;
    const int lr = lane & 15, cb = lane >> 4;
    const int arow = tid >> 2, ach = (tid & 3) * 8;

    f32x4 acc[4][4];
#pragma unroll
    for (int i = 0; i < 4; ++i)
#pragma unroll
        for (int j = 0; j < 4; ++j) acc[i][j] = (f32x4){0.f,0.f,0.f,0.f};

    int4 pA, pB0, pB1, pB2, pB3;

#define GEMM_ISSUE(C0)                                                        \
    {                                                                         \
        pA = *(const int4*)&A[(size_t)(o0 + arow)*C_ + (C0) + ach];           \
        pB0 = *(const int4*)&Bt[((size_t)n*HW_ + p0 + arow      )*C_ + (C0) + ach]; \
        pB1 = *(const int4*)&Bt[((size_t)n*HW_ + p0 + arow +  64)*C_ + (C0) + ach]; \
        pB2 = *(const int4*)&Bt[((size_t)n*HW_ + p0 + arow + 128)*C_ + (C0) + ach]; \
        pB3 = *(const int4*)&Bt[((size_t)n*HW_ + p0 + arow + 192)*C_ + (C0) + ach]; \
    }

    GEMM_ISSUE(0)
    for (int c0 = 0; c0 < C_; c0 += 32) {
        *(int4*)&aL[arow][ach] = pA;
        *(int4*)&bL[arow      ][ach] = pB0;
        *(int4*)&bL[arow +  64][ach] = pB1;
        *(int4*)&bL[arow + 128][ach] = pB2;
        *(int4*)&bL[arow + 192][ach] = pB3;
        __syncthreads();
        if (c0 + 32 < C_) GEMM_ISSUE(c0 + 32)    // overlap with MFMA below
        bf16x8 af[4], bfv[4];
#pragma unroll
        for (int fo = 0; fo < 4; ++fo)
            af[fo] = *(const bf16x8*)&aL[fo*16 + lr][cb*8];
#pragma unroll
        for (int fp = 0; fp < 4; ++fp)
            bfv[fp] = *(const bf16x8*)&bL[wid*64 + fp*16 + lr][cb*8];
#pragma unroll
        for (int fo = 0; fo < 4; ++fo)
#pragma unroll
            for (int fp = 0; fp < 4; ++fp)
                acc[fo][fp] = __builtin_amdgcn_mfma_f32_16x16x32_bf16(
                    af[fo], bfv[fp], acc[fo][fp], 0, 0, 0);
        __syncthreads();
    }
#undef GEMM_ISSUE
#pragma unroll
    for (int fo = 0; fo < 4; ++fo) {
        const int obase = o0 + fo*16 + cb*4;
        const bool isq = isqk && !(obase >> 6);
        const float* bp = isqk ? ((obase >> 6) ? bk : bq) : bv;
        const int bofs = isqk ? (obase & 63) : obase;
        float bv4[4];
#pragma unroll
        for (int r = 0; r < 4; ++r) bv4[r] = bp[bofs + r];
#pragma unroll
        for (int fp = 0; fp < 4; ++fp) {
            int p = p0 + wid*64 + fp*16 + lr;
            float v[4];
#pragma unroll
            for (int r = 0; r < 4; ++r) {
                v[r] = acc[fo][fp][r] + bv4[r];
                if (isq) v[r] *= 1.44269504f;     // log2(e): pv uses exp2
            }
            if (isqk) {
                uint2 u;
                u.x = (unsigned)bfb(v[0]) | ((unsigned)bfb(v[1]) << 16);
                u.y = (unsigned)bfb(v[2]) | ((unsigned)bfb(v[3]) << 16);
                size_t base = (((size_t)((obase >> 6) * N_ + n))*HW_ + p)*64
                              + (obase & 63);
                *(uint2*)&qkb[base] = u;
            } else {
#pragma unroll
                for (int r = 0; r < 4; ++r)
                    vb[((size_t)(n*C_ + obase + r))*HW_ + p] =
                        __float2bfloat16(v[r]);
            }
        }
    }
}

// ---------------------------------------------------------------------------
// MERGED tail projections, cmlp FOLDED IN: one launch, grid (16,2,4).
// ---------------------------------------------------------------------------
__global__ __launch_bounds__(256, 2) void k_gemm_tail(
    const bf16s* __restrict__ Wpob, const bf16s* __restrict__ Wcob,
    const bf16s* __restrict__ featT, const bf16s* __restrict__ featT2,
    const float* __restrict__ b_pam, const float* __restrict__ b_cam,
    const float* __restrict__ s0, const float* __restrict__ Wc1,
    const float* __restrict__ bc1, const float* __restrict__ Wc2,
    const float* __restrict__ bc2,
    float* __restrict__ pam_low, float* __restrict__ cam_low)
{
    __shared__ bf16s aL[64][36];
    __shared__ bf16s bL[256][36];
    __shared__ float s2s[C_];
    __shared__ float s1s[CR_];
    const int tid = threadIdx.x;
    const int half = blockIdx.y;
    const int n  = blockIdx.z;
    const int p0 = blockIdx.x * 256;
    const bf16s* A = half ? Wcob : Wpob;
    const bf16s* Bt = half ? featT2 : featT;
    const float* bias = half ? b_cam : b_pam;
    float* outp = half ? cam_low : pam_low;
    const int lane = tid & 63;
    const int wid  = tid >> 6;
    const int lr = lane & 15, cb = lane >> 4;
    const int arow = tid >> 2, ach = (tid & 3) * 8;

    if (half) {                              // recompute s2 (CAM MLP) in-block
        if (tid < CR_) {
            float a = 0.f;
            for (int c = 0; c < C_; ++c)
                a = fmaf(Wc1[(size_t)tid*C_ + c], s0[n*C_ + c] * (1.f/HW_), a);
            a += bc1[tid];
            s1s[tid] = a > 0.f ? a : 0.2f*a;
        }
        __syncthreads();
        for (int c = tid; c < C_; c += 256) {
            float bb = 0.f;
            for (int i = 0; i < CR_; ++i)
                bb = fmaf(Wc2[(size_t)c*CR_ + i], s1s[i], bb);
            bb += bc2[c];
            s2s[c] = 1.f / (1.f + __expf(-bb));
        }
        __syncthreads();
    }

    f32x4 acc[4][4];
#pragma unroll
    for (int i = 0; i < 4; ++i)
#pragma unroll
        for (int j = 0; j < 4; ++j) acc[i][j] = (f32x4){0.f,0.f,0.f,0.f};

    int4 pA, pB0, pB1, pB2, pB3;

#define GEMM_ISSUE(C0)                                                        \
    {                                                                         \
        pA = *(const int4*)&A[(size_t)arow*C_ + (C0) + ach];                  \
        pB0 = *(const int4*)&Bt[((size_t)n*HW_ + p0 + arow      )*C_ + (C0) + ach]; \
        pB1 = *(const int4*)&Bt[((size_t)n*HW_ + p0 + arow +  64)*C_ + (C0) + ach]; \
        pB2 = *(const int4*)&Bt[((size_t)n*HW_ + p0 + arow + 128)*C_ + (C0) + ach]; \
        pB3 = *(const int4*)&Bt[((size_t)n*HW_ + p0 + arow + 192)*C_ + (C0) + ach]; \
    }

    GEMM_ISSUE(0)
    for (int c0 = 0; c0 < C_; c0 += 32) {
        if (half) {
            const bf16s* sp = (const bf16s*)&pA;
            bf16s tmp[8];
#pragma unroll
            for (int u = 0; u < 8; ++u)
                tmp[u] = __float2bfloat16(
                    __bfloat162float(sp[u]) * s2s[c0 + ach + u]);
            *(int4*)&aL[arow][ach] = *(int4*)tmp;
        } else {
            *(int4*)&aL[arow][ach] = pA;
        }
        *(int4*)&bL[arow      ][ach] = pB0;
        *(int4*)&bL[arow +  64][ach] = pB1;
        *(int4*)&bL[arow + 128][ach] = pB2;
        *(int4*)&bL[arow + 192][ach] = pB3;
        __syncthreads();
        if (c0 + 32 < C_) GEMM_ISSUE(c0 + 32)    // overlap with MFMA below
        bf16x8 af[4], bfv[4];
#pragma unroll
        for (int fo = 0; fo < 4; ++fo)
            af[fo] = *(const bf16x8*)&aL[fo*16 + lr][cb*8];
#pragma unroll
        for (int fp = 0; fp < 4; ++fp)
            bfv[fp] = *(const bf16x8*)&bL[wid*64 + fp*16 + lr][cb*8];
#pragma unroll
        for (int fo = 0; fo < 4; ++fo)
#pragma unroll
            for (int fp = 0; fp < 4; ++fp)
                acc[fo][fp] = __builtin_amdgcn_mfma_f32_16x16x32_bf16(
                    af[fo], bfv[fp], acc[fo][fp], 0, 0, 0);
        __syncthreads();
    }
#undef GEMM_ISSUE
#pragma unroll
    for (int fo = 0; fo < 4; ++fo) {
        const int obase = fo*16 + cb*4;
        float bv[4];
#pragma unroll
        for (int r = 0; r < 4; ++r) bv[r] = bias[obase + r];
#pragma unroll
        for (int fp = 0; fp < 4; ++fp) {
            int p = p0 + wid*64 + fp*16 + lr;
#pragma unroll
            for (int r = 0; r < 4; ++r)
                outp[((size_t)(n*NC_ + obase + r))*HW_ + p] =
                    acc[fo][fp][r] + bv[r];
        }
    }
}

// ---------------------------------------------------------------------------
// pass B, FULL FLASH (R13-verified, R14 +setprio, R17 exp2+defer-max).
// ---------------------------------------------------------------------------
__global__ __launch_bounds__(256, 4) void k_pv_mfma(
    const bf16s* __restrict__ qb, const bf16s* __restrict__ kb,
    const bf16s* __restrict__ vb, const float* __restrict__ alpha,
    bf16s* __restrict__ featT)
{
    __shared__ bf16s ks[2][4096];
    __shared__ bf16s ps[2][4096];
    __shared__ float sfl[2][64];                 // per-column rescale factors
    __shared__ float lfin[64];                   // final denominators
    const int tid = threadIdx.x;
    const int lid = blockIdx.x + (blockIdx.y << 6) + (blockIdx.z << 8);
    const int k8  = lid & 7;
    const int n   = k8 >> 1;
    const int cc0 = (((lid >> 3) & 1) * 2 + (k8 & 1)) << 7;   // {0,128,256,384}
    const int i0  = (lid >> 4) << 6;
    const int lane = tid & 63;
    const int wid  = tid >> 6;
    const int lr = lane & 15, cb = lane >> 4;

    // stage Q into ks[0] (overwritten with K(0) after frag read)
    for (int e = tid; e < 512; e += 256) {
        int row = e >> 3, ch = e & 7;
        *(int4*)&ks[0][swz8(row, ch)] =
            *(const int4*)&qb[((size_t)n*HW_ + i0 + row)*CR_ + ch*8];
    }
    const int krow = tid >> 3, kch = tid & 7;
    const bf16s* kbase = kb + (size_t)n*HW_*CR_ + kch*8;
    int4 kreg0 = *(const int4*)(kbase + (size_t)krow*CR_);
    int4 kreg1 = *(const int4*)(kbase + (size_t)(krow + 32)*CR_);
    __syncthreads();                             // Q visible
    bf16x8 bq[2];                                // loop-invariant Q fragments
#pragma unroll
    for (int kk = 0; kk < 2; ++kk)
        bq[kk] = *(const bf16x8*)&ks[0][swz8(wid*16 + lr, kk*4 + cb)];

    const float al = alpha[0];
    __syncthreads();                             // Q frag reads done
    *(int4*)&ks[0][swz8(krow, kch)] = kreg0;     // commit K(0)
    *(int4*)&ks[0][swz8(krow + 32, kch)] = kreg1;
    kreg0 = *(const int4*)(kbase + (size_t)(64 + krow)*CR_);       // K(1)
    kreg1 = *(const int4*)(kbase + (size_t)(64 + krow + 32)*CR_);
    __syncthreads();                             // ks[0]=K(0) visible

    f32x4 acc[2][4];                             // [fc2][fi]
#pragma unroll
    for (int i = 0; i < 2; ++i)
#pragma unroll
        for (int j = 0; j < 4; ++j) acc[i][j] = (f32x4){0.f,0.f,0.f,0.f};

    float m_run = -INFINITY, l_run = 0.f;        // stats for column i0+wid*16+lr

    const bf16s* vbase = vb + ((size_t)(n*C_ + cc0 + wid*32))*HW_;
    bf16x8 vc0, vc1, vc2, vc3, vn0, vn1, vn2, vn3;

    for (int jt = 0; jt < 64; ++jt) {
        // 1. issue V(jt) loads (independent; consumed next iteration)
        const bf16s* vj = vbase + jt*64;
        vn0 = *(const bf16x8*)(vj + (size_t)(     lr)*HW_      + cb*8);
        vn1 = *(const bf16x8*)(vj + (size_t)(16 + lr)*HW_      + cb*8);
        vn2 = *(const bf16x8*)(vj + (size_t)(     lr)*HW_ + 32 + cb*8);
        vn3 = *(const bf16x8*)(vj + (size_t)(16 + lr)*HW_ + 32 + cb*8);
        // 2. PV(jt-1): rescale acc by f(jt-1), then MFMA on ps[(jt-1)&1]
        if (jt > 0) {
            const float* fs = sfl[(jt - 1) & 1];
            const bf16s* pp = ps[(jt - 1) & 1];
            bf16x8 pa[4];
#pragma unroll
            for (int fi = 0; fi < 4; ++fi) {
                const float f = fs[fi*16 + lr];
#pragma unroll
                for (int r = 0; r < 4; ++r) {
                    acc[0][fi][r] *= f;
                    acc[1][fi][r] *= f;
                }
            }
#pragma unroll
            for (int fi = 0; fi < 4; ++fi)
                pa[fi] = *(const bf16x8*)&pp[swz8(fi*16 + lr, cb)];
            __builtin_amdgcn_s_setprio(1);
#pragma unroll
            for (int fi = 0; fi < 4; ++fi) {
                acc[0][fi] = __builtin_amdgcn_mfma_f32_16x16x32_bf16(
                    vc0, pa[fi], acc[0][fi], 0, 0, 0);
                acc[1][fi] = __builtin_amdgcn_mfma_f32_16x16x32_bf16(
                    vc1, pa[fi], acc[1][fi], 0, 0, 0);
            }
            __builtin_amdgcn_s_setprio(0);
#pragma unroll
            for (int fi = 0; fi < 4; ++fi)
                pa[fi] = *(const bf16x8*)&pp[swz8(fi*16 + lr, 4 + cb)];
            __builtin_amdgcn_s_setprio(1);
#pragma unroll
            for (int fi = 0; fi < 4; ++fi) {
                acc[0][fi] = __builtin_amdgcn_mfma_f32_16x16x32_bf16(
                    vc2, pa[fi], acc[0][fi], 0, 0, 0);
                acc[1][fi] = __builtin_amdgcn_mfma_f32_16x16x32_bf16(
                    vc3, pa[fi], acc[1][fi], 0, 0, 0);
            }
            __builtin_amdgcn_s_setprio(0);
        }
        // 3. S^T(jt) from ks[jt&1]; online column stats (log2 domain);
        //    P = exp2(s - m_run) -> ps[jt&1]
        {
            const bf16s* kst = ks[jt & 1];
            bf16s* pst = ps[jt & 1];
            f32x4 sv0 = (f32x4){0.f,0.f,0.f,0.f};
            f32x4 sv1 = (f32x4){0.f,0.f,0.f,0.f};
            f32x4 sv2 = (f32x4){0.f,0.f,0.f,0.f};
            f32x4 sv3 = (f32x4){0.f,0.f,0.f,0.f};
            sv0 = __builtin_amdgcn_mfma_f32_16x16x32_bf16(
                *(const bf16x8*)&kst[swz8(     lr, cb)], bq[0], sv0, 0, 0, 0);
            sv0 = __builtin_amdgcn_mfma_f32_16x16x32_bf16(
                *(const bf16x8*)&kst[swz8(     lr, 4 + cb)], bq[1], sv0, 0, 0, 0);
            sv1 = __builtin_amdgcn_mfma_f32_16x16x32_bf16(
                *(const bf16x8*)&kst[swz8(16 + lr, cb)], bq[0], sv1, 0, 0, 0);
            sv1 = __builtin_amdgcn_mfma_f32_16x16x32_bf16(
                *(const bf16x8*)&kst[swz8(16 + lr, 4 + cb)], bq[1], sv1, 0, 0, 0);
            sv2 = __builtin_amdgcn_mfma_f32_16x16x32_bf16(
                *(const bf16x8*)&kst[swz8(32 + lr, cb)], bq[0], sv2, 0, 0, 0);
            sv2 = __builtin_amdgcn_mfma_f32_16x16x32_bf16(
                *(const bf16x8*)&kst[swz8(32 + lr, 4 + cb)], bq[1], sv2, 0, 0, 0);
            sv3 = __builtin_amdgcn_mfma_f32_16x16x32_bf16(
                *(const bf16x8*)&kst[swz8(48 + lr, cb)], bq[0], sv3, 0, 0, 0);
            sv3 = __builtin_amdgcn_mfma_f32_16x16x32_bf16(
                *(const bf16x8*)&kst[swz8(48 + lr, 4 + cb)], bq[1], sv3, 0, 0, 0);
            // column max over this thread's 16 j's, then over cb group
            float tmax = sv0[0];
#pragma unroll
            for (int r = 0; r < 4; ++r) {
                tmax = fmaxf(tmax, sv0[r]); tmax = fmaxf(tmax, sv1[r]);
                tmax = fmaxf(tmax, sv2[r]); tmax = fmaxf(tmax, sv3[r]);
            }
            tmax = fmaxf(tmax, __shfl_xor(tmax, 16));
            tmax = fmaxf(tmax, __shfl_xor(tmax, 32));
            float fsc;
            if (tmax > m_run + 11.5f) {          // T13 defer-max (8 nats)
                fsc = ex2(m_run - tmax);         // 0 on first tile
                m_run = tmax;
            } else {
                fsc = 1.f;
            }
            float tsum = 0.f;
#define PV_PACK(SV, FJ)                                                       \
            {                                                                 \
                float p0_ = ex2(SV[0] - m_run), p1_ = ex2(SV[1] - m_run);     \
                float p2_ = ex2(SV[2] - m_run), p3_ = ex2(SV[3] - m_run);     \
                tsum += (p0_ + p1_) + (p2_ + p3_);                            \
                uint2 u;                                                      \
                u.x = (unsigned)bfb(p0_) | ((unsigned)bfb(p1_) << 16);        \
                u.y = (unsigned)bfb(p2_) | ((unsigned)bfb(p3_) << 16);        \
                *(uint2*)&pst[swz8(wid*16 + lr, FJ*2 + (cb >> 1)) + (cb & 1)*4] = u; \
            }
            PV_PACK(sv0, 0)
            PV_PACK(sv1, 1)
            PV_PACK(sv2, 2)
            PV_PACK(sv3, 3)
#undef PV_PACK
            tsum += __shfl_xor(tsum, 16);
            tsum += __shfl_xor(tsum, 32);
            l_run = l_run * fsc + tsum;
            if (cb == 0) sfl[jt & 1][wid*16 + lr] = fsc;
        }
        // 4. commit K(jt+1), prefetch K(jt+2)
        if (jt < 63) {
            *(int4*)&ks[(jt + 1) & 1][swz8(krow, kch)] = kreg0;
            *(int4*)&ks[(jt + 1) & 1][swz8(krow + 32, kch)] = kreg1;
            if (jt < 62) {
                kreg0 = *(const int4*)(kbase + (size_t)((jt+2)*64 + krow)*CR_);
                kreg1 = *(const int4*)(kbase + (size_t)((jt+2)*64 + krow + 32)*CR_);
            }
        }
        // 5. rotate V regs
        vc0 = vn0; vc1 = vn1; vc2 = vn2; vc3 = vn3;
        __syncthreads();                         // ps/sfl(jt) visible
    }
    // publish final denominators
    if (cb == 0) lfin[wid*16 + lr] = l_run;
    // epilogue PV(63): rescale by f(63) then MFMA
    {
        const float* fs = sfl[1];
        const bf16s* pp = ps[1];
        bf16x8 pa[4];
#pragma unroll
        for (int fi = 0; fi < 4; ++fi) {
            const float f = fs[fi*16 + lr];
#pragma unroll
            for (int r = 0; r < 4; ++r) {
                acc[0][fi][r] *= f;
                acc[1][fi][r] *= f;
            }
        }
#pragma unroll
        for (int fi = 0; fi < 4; ++fi)
            pa[fi] = *(const bf16x8*)&pp[swz8(fi*16 + lr, cb)];
#pragma unroll
        for (int fi = 0; fi < 4; ++fi) {
            acc[0][fi] = __builtin_amdgcn_mfma_f32_16x16x32_bf16(
                vc0, pa[fi], acc[0][fi], 0, 0, 0);
            acc[1][fi] = __builtin_amdgcn_mfma_f32_16x16x32_bf16(
                vc1, pa[fi], acc[1][fi], 0, 0, 0);
        }
#pragma unroll
        for (int fi = 0; fi < 4; ++fi)
            pa[fi] = *(const bf16x8*)&pp[swz8(fi*16 + lr, 4 + cb)];
#pragma unroll
        for (int fi = 0; fi < 4; ++fi) {
            acc[0][fi] = __builtin_amdgcn_mfma_f32_16x16x32_bf16(
                vc2, pa[fi], acc[0][fi], 0, 0, 0);
            acc[1][fi] = __builtin_amdgcn_mfma_f32_16x16x32_bf16(
                vc3, pa[fi], acc[1][fi], 0, 0, 0);
        }
    }
    __syncthreads();                             // lfin visible
    // epilogue: normalize + residual add (bf16 featT RMW) + uint2 stores
#pragma unroll
    for (int fc2 = 0; fc2 < 2; ++fc2) {
        const int ccl = wid*32 + fc2*16 + cb*4;
#pragma unroll
        for (int fi = 0; fi < 4; ++fi) {
            const int p = i0 + fi*16 + lr;
            const float rv = al / lfin[fi*16 + lr];
            bf16s* fb = &featT[((size_t)n*HW_ + p)*C_ + cc0 + ccl];
            uint2 fv = *(const uint2*)fb;
            float f0 = b2f((unsigned short)(fv.x & 0xffff));
            float f1 = b2f((unsigned short)(fv.x >> 16));
            float f2 = b2f((unsigned short)(fv.y & 0xffff));
            float f3 = b2f((unsigned short)(fv.y >> 16));
            float v0 = fmaf(rv, acc[fc2][fi][0], f0);
            float v1 = fmaf(rv, acc[fc2][fi][1], f1);
            float v2 = fmaf(rv, acc[fc2][fi][2], f2);
            float v3 = fmaf(rv, acc[fc2][fi][3], f3);
            uint2 u;
            u.x = (unsigned)bfb(v0) | ((unsigned)bfb(v1) << 16);
            u.y = (unsigned)bfb(v2) | ((unsigned)bfb(v3) << 16);
            *(uint2*)fb = u;
        }
    }
}

// ---------------------------------------------------------------------------
__global__ __launch_bounds__(256) void k_up(
    const float* __restrict__ pl, const float* __restrict__ cl,
    float* __restrict__ out)
{
    int idx = blockIdx.x * 256 + threadIdx.x;
    int ox = idx & 127; int rest = idx >> 7;
    int oy = rest & 127; rest >>= 7;
    int o  = rest & 63;  int n = rest >> 6;
    float fy = oy*0.5f - 0.25f;
    float fx = ox*0.5f - 0.25f;
    int y0 = (int)floorf(fy); float wy = fy - y0;
    int x0 = (int)floorf(fx); float wx = fx - x0;
    int y0c = y0 < 0 ? 0 : y0;      int y1c = y0+1 > 63 ? 63 : y0+1;
    int x0c = x0 < 0 ? 0 : x0;      int x1c = x0+1 > 63 ? 63 : x0+1;
    const float* a = pl + ((size_t)(n*NC_ + o))*HW_;
    const float* b = cl + ((size_t)(n*NC_ + o))*HW_;
    float v00 = a[y0c*64+x0c] + b[y0c*64+x0c];
    float v01 = a[y0c*64+x1c] + b[y0c*64+x1c];
    float v10 = a[y1c*64+x0c] + b[y1c*64+x0c];
    float v11 = a[y1c*64+x1c] + b[y1c*64+x1c];
    out[idx] = (1.f-wy)*((1.f-wx)*v00 + wx*v01) + wy*((1.f-wx)*v10 + wx*v11);
}

// ---------------------------------------------------------------------------
extern "C" void kernel_launch(void* const* d_in, const int* in_sizes, int n_in,
                              void* d_out, int out_size, void* d_ws, size_t ws_size,
                              hipStream_t stream)
{
    const float* x         = (const float*)d_in[0];
    const float* W_pam_in  = (const float*)d_in[1];
    const float* pam_g     = (const float*)d_in[2];
    const float* pam_b     = (const float*)d_in[3];
    const float* pam_m     = (const float*)d_in[4];
    const float* pam_v     = (const float*)d_in[5];
    const float* Wq        = (const float*)d_in[6];
    const float* bq        = (const float*)d_in[7];
    const float* Wk        = (const float*)d_in[8];
    const float* bk        = (const float*)d_in[9];
    const float* Wv        = (const float*)d_in[10];
    const float* bv        = (const float*)d_in[11];
    const float* alpha     = (const float*)d_in[12];
    const float* W_pam_out = (const float*)d_in[13];
    const float* b_pam_out = (const float*)d_in[14];
    const float* W_cam_in  = (const float*)d_in[15];
    const float* cam_g     = (const float*)d_in[16];
    const float* cam_b     = (const float*)d_in[17];
    const float* cam_m     = (const float*)d_in[18];
    const float* cam_v     = (const float*)d_in[19];
    const float* Wc1       = (const float*)d_in[20];
    const float* bc1       = (const float*)d_in[21];
    const float* Wc2       = (const float*)d_in[22];
    const float* bc2       = (const float*)d_in[23];
    const float* W_cam_out = (const float*)d_in[24];
    const float* b_cam_out = (const float*)d_in[25];

    float* pam_low = (float*)d_ws;             // [4][64][4096]
    float* s0      = pam_low + 1048576;        // [4][512]
    bf16s* xbT     = (bf16s*)(s0 + 2048);      // [4][4096][512] bf16
    bf16s* featTb  = xbT + 8388608;            // [4][4096][512] (PAM)
    bf16s* featTb2 = featTb + 8388608;         // [4][4096][512] (CAM)
    bf16s* vb      = featTb2 + 8388608;        // [4][512][4096]
    bf16s* qb      = vb + 8388608;             // [4][4096][64]
    bf16s* kb      = qb + 1048576;             // adjacent to qb (qkv fuse)
    bf16s* wbp     = kb + 1048576;             // [512][9][512] PAM
    bf16s* wbp2    = wbp + 2359296;            // [512][9][512] CAM
    bf16s* Wqb     = wbp2 + 2359296;           // [64][512]
    bf16s* Wkb     = Wqb + 32768;              // adjacent to Wqb (concat A)
    bf16s* Wvb     = Wkb + 32768;              // [512][512]
    bf16s* Wpob    = Wvb + 262144;             // [64][512]
    bf16s* Wcob    = Wpob + 32768;             // [64][512]
    float* cam_low = (float*)qb;               // aliases qb+kb (dead after pv)

    dim3 b256(256);
    // merged prologue: weight prep + s0 zero + x transpose, one launch
    k_prep<<<dim3(22024), b256, 0, stream>>>(
        x, W_pam_in, W_cam_in, Wq, Wk, Wv, W_pam_out, W_cam_out,
        xbT, wbp, wbp2, Wqb, Wkb, Wvb, Wpob, Wcob, s0);
    // merged PAM+CAM conv, XCD-swizzled, single-buffer (R10-verified)
    k_conv3x3_mfma<<<dim3(32,8,4), b256, 0, stream>>>(
        xbT, wbp, wbp2, pam_g, pam_b, pam_m, pam_v,
        cam_g, cam_b, cam_m, cam_v, featTb, featTb2, s0);
    // merged Q+K+V gemm, XCD-swizzled (Q scaled by log2e for exp2 flash)
    k_gemm_qkv<<<dim3(16,10,4), b256, 0, stream>>>(
        Wqb, Wvb, featTb, bq, bk, bv, qb, vb);
    // flash attention (exp2 domain, T13 defer-max)
    k_pv_mfma<<<dim3(64,4,4), b256, 0, stream>>>(
        qb, kb, vb, alpha, featTb);
    // merged tail projections with cmlp folded in (128 blocks)
    k_gemm_tail<<<dim3(16,2,4), b256, 0, stream>>>(
        Wpob, Wcob, featTb, featTb2, b_pam_out, b_cam_out,
        s0, Wc1, bc1, Wc2, bc2, pam_low, cam_low);
    // upsample + add
    k_up<<<dim3(16384), b256, 0, stream>>>(pam_low, cam_low, (float*)d_out);
}